// Round 3
// baseline (1429.954 us; speedup 1.0000x reference)
//
#include <hip/hip_runtime.h>
#include <hip/hip_bf16.h>
#include <math.h>
#include <stdint.h>

// Problem constants
constexpr int N_ROWS = 32768;
constexpr int K_DIM  = 4096;
constexpr int R_DIM  = 256;
constexpr int KP     = 3 * R_DIM;   // 768: split-K' for [hi|hi|lo] x [hi|lo|hi]

typedef __bf16 bf16x8 __attribute__((ext_vector_type(8)));
typedef float  f32x4  __attribute__((ext_vector_type(4)));
typedef unsigned short u16x8 __attribute__((ext_vector_type(8)));
typedef unsigned short u16x4 __attribute__((ext_vector_type(4)));

// ---- bf16 helpers (round-to-nearest-even) ----
__device__ __forceinline__ unsigned short f2bf(float x) {
    unsigned u = __float_as_uint(x);
    u += 0x7fffu + ((u >> 16) & 1u);
    return (unsigned short)(u >> 16);
}
__device__ __forceinline__ float bf2f(unsigned short h) {
    return __uint_as_float((unsigned)h << 16);
}

// ---- async global->LDS, 16B/lane, LDS dest = wave-uniform base + lane*16
__device__ __forceinline__ void gl2lds16(const void* gptr, void* lptr) {
    __builtin_amdgcn_global_load_lds(
        (const __attribute__((address_space(1))) unsigned int*)gptr,
        (__attribute__((address_space(3))) unsigned int*)lptr,
        16, 0, 0);
}

// ===========================================================================
// MFMA NT GEMM: C[m,n] = sum_k A[m,k]*B[n,k], bf16 in, fp32 out.
// 128x128 tile, BK=32, 4 waves (2x2 of 64x64), 16x16x32 MFMA.
// Grid: x = N-tile (fast-varying -> A-strip L2 reuse), y = M-tile.
// STATS: also emit per-(row, N-tile) partial softmax stats (max, sum-exp).
// ===========================================================================
template<bool STATS>
__global__ __launch_bounds__(256)
void gemm_mfma_nt(const unsigned short* __restrict__ A,
                  const unsigned short* __restrict__ B,
                  float* __restrict__ C, int M, int N, int Kc,
                  float* __restrict__ partM, float* __restrict__ partL)
{
    __shared__ __align__(16) unsigned short As[128 * 32];
    __shared__ __align__(16) unsigned short Bs[128 * 32];

    const int tid  = threadIdx.x;
    const int wave = tid >> 6, lane = tid & 63;
    const int wm = wave >> 1, wn = wave & 1;
    const long m0 = (long)blockIdx.y * 128;
    const long n0 = (long)blockIdx.x * 128;

    f32x4 acc[4][4] = {};

    const int srow  = lane >> 2;
    const int skoff = (lane & 3) * 8;
    const int c0 = wave, c1 = wave + 4;
    const int kq = (lane >> 4) * 8;
    const int mr = lane & 15;

    for (int k0 = 0; k0 < Kc; k0 += 32) {
        gl2lds16(A + (m0 + c0 * 16 + srow) * (long)Kc + k0 + skoff, &As[c0 * 512]);
        gl2lds16(A + (m0 + c1 * 16 + srow) * (long)Kc + k0 + skoff, &As[c1 * 512]);
        gl2lds16(B + (n0 + c0 * 16 + srow) * (long)Kc + k0 + skoff, &Bs[c0 * 512]);
        gl2lds16(B + (n0 + c1 * 16 + srow) * (long)Kc + k0 + skoff, &Bs[c1 * 512]);
        __syncthreads();

        bf16x8 af[4], bfr[4];
#pragma unroll
        for (int t = 0; t < 4; ++t) {
            af[t]  = *(const bf16x8*)&As[(wm * 64 + t * 16 + mr) * 32 + kq];
            bfr[t] = *(const bf16x8*)&Bs[(wn * 64 + t * 16 + mr) * 32 + kq];
        }
#pragma unroll
        for (int i = 0; i < 4; ++i)
#pragma unroll
            for (int j = 0; j < 4; ++j)
                acc[i][j] = __builtin_amdgcn_mfma_f32_16x16x32_bf16(
                    af[i], bfr[j], acc[i][j], 0, 0, 0);
        __syncthreads();
    }

    // C/D layout: col = lane&15, row = (lane>>4)*4 + reg
    const int col = lane & 15, rquad = (lane >> 4) * 4;
#pragma unroll
    for (int i = 0; i < 4; ++i) {
        const long mrow = m0 + wm * 64 + i * 16 + rquad;
#pragma unroll
        for (int j = 0; j < 4; ++j) {
            float* p = C + mrow * (long)N + n0 + wn * 64 + j * 16 + col;
#pragma unroll
            for (int r = 0; r < 4; ++r) p[(long)r * N] = acc[i][j][r];
        }
    }

    if constexpr (STATS) {
        __shared__ float sm[2][128];
        __shared__ float sl[2][128];
        float mx[4][4];
        // per-row max over this wave's 64 cols
#pragma unroll
        for (int i = 0; i < 4; ++i)
#pragma unroll
            for (int r = 0; r < 4; ++r) {
                float m_ = fmaxf(fmaxf(acc[i][0][r], acc[i][1][r]),
                                 fmaxf(acc[i][2][r], acc[i][3][r]));
#pragma unroll
                for (int off = 1; off < 16; off <<= 1)
                    m_ = fmaxf(m_, __shfl_xor(m_, off));
                mx[i][r] = m_;
            }
        if ((lane & 15) == 0) {
#pragma unroll
            for (int i = 0; i < 4; ++i)
#pragma unroll
                for (int r = 0; r < 4; ++r)
                    sm[wn][wm * 64 + i * 16 + rquad + r] = mx[i][r];
        }
        __syncthreads();
        float sx[4][4];
#pragma unroll
        for (int i = 0; i < 4; ++i)
#pragma unroll
            for (int r = 0; r < 4; ++r) {
                const int row = wm * 64 + i * 16 + rquad + r;
                const float mc = fmaxf(sm[0][row], sm[1][row]);
                float s_ = __expf(acc[i][0][r] - mc) + __expf(acc[i][1][r] - mc)
                         + __expf(acc[i][2][r] - mc) + __expf(acc[i][3][r] - mc);
#pragma unroll
                for (int off = 1; off < 16; off <<= 1)
                    s_ += __shfl_xor(s_, off);
                sx[i][r] = s_; mx[i][r] = mc;
            }
        if ((lane & 15) == 0) {
#pragma unroll
            for (int i = 0; i < 4; ++i)
#pragma unroll
                for (int r = 0; r < 4; ++r)
                    sl[wn][wm * 64 + i * 16 + rquad + r] = sx[i][r];
        }
        __syncthreads();
        if (wn == 0 && (lane & 15) == 0) {
#pragma unroll
            for (int i = 0; i < 4; ++i)
#pragma unroll
                for (int r = 0; r < 4; ++r) {
                    const int row = wm * 64 + i * 16 + rquad + r;
                    const long g = (m0 + row) * 32 + blockIdx.x;
                    partM[g] = mx[i][r];
                    partL[g] = sl[0][row] + sl[1][row];
                }
        }
    }
}

// ===========================================================================
// Combine 32 per-tile (m,l) partials per row -> rowM, rowInv = 1/sum.
// ===========================================================================
__global__ __launch_bounds__(256)
void stats_combine(const float* __restrict__ partM, const float* __restrict__ partL,
                   float* __restrict__ rowM, float* __restrict__ rowInv)
{
    const int row = blockIdx.x * 256 + threadIdx.x;
    const float* pm = partM + (long)row * 32;
    const float* pl = partL + (long)row * 32;
    float m = -3.4e38f;
#pragma unroll
    for (int i = 0; i < 32; ++i) m = fmaxf(m, pm[i]);
    float L = 0.f;
#pragma unroll
    for (int i = 0; i < 32; ++i) L += pl[i] * __expf(pm[i] - m);
    rowM[row] = m;
    rowInv[row] = 1.f / L;
}

// ===========================================================================
// Fused: A = exp(M - rowM)*rowInv (write back in place, fp32 output) and
// C = A @ L via MFMA with bf16(A) and pre-transposed bf16 LT (R x K).
// 32-row strips, 256 threads = 4 waves, each wave 32 rows x 64 cols of C.
// ===========================================================================
__global__ __launch_bounds__(256)
void fused_aw(float* __restrict__ Mio, const unsigned short* __restrict__ LT,
              const float* __restrict__ rowM, const float* __restrict__ rowInv,
              float* __restrict__ C)
{
    __shared__ __align__(16) unsigned short As[32 * 32];
    __shared__ __align__(16) unsigned short Bs[256 * 32];

    const int tid = threadIdx.x, wave = tid >> 6, lane = tid & 63;
    const long m0 = (long)blockIdx.x * 32;

    const int arow = tid >> 3;           // 0..31
    const int acol = (tid & 7) * 4;      // 0..28
    const float rm = rowM[m0 + arow];
    const float ri = rowInv[m0 + arow];
    float* Mrow = Mio + (m0 + arow) * (long)K_DIM + acol;

    const int srow = lane >> 2, skoff = (lane & 3) * 8;
    const int kq = (lane >> 4) * 8, mr = lane & 15;

    f32x4 acc[2][4] = {};

    for (int k0 = 0; k0 < K_DIM; k0 += 32) {
        // stage L^T chunk (256 rows x 32 k, bf16) via async DMA
#pragma unroll
        for (int c4 = 0; c4 < 4; ++c4) {
            const int c = wave * 4 + c4;
            gl2lds16(LT + (c * 16 + srow) * (long)K_DIM + k0 + skoff, &Bs[c * 512]);
        }
        // stage A chunk: read M, exp-normalize, write A back, bf16 to LDS
        float4 v = *(const float4*)(Mrow + k0);
        float4 a;
        a.x = __expf(v.x - rm) * ri;
        a.y = __expf(v.y - rm) * ri;
        a.z = __expf(v.z - rm) * ri;
        a.w = __expf(v.w - rm) * ri;
        *(float4*)(Mrow + k0) = a;
        u16x4 u;
        u[0] = f2bf(a.x); u[1] = f2bf(a.y); u[2] = f2bf(a.z); u[3] = f2bf(a.w);
        *(u16x4*)&As[arow * 32 + acol] = u;
        __syncthreads();

        bf16x8 af[2], bfr[4];
        af[0] = *(const bf16x8*)&As[(mr) * 32 + kq];
        af[1] = *(const bf16x8*)&As[(16 + mr) * 32 + kq];
#pragma unroll
        for (int j = 0; j < 4; ++j)
            bfr[j] = *(const bf16x8*)&Bs[(wave * 64 + j * 16 + mr) * 32 + kq];
#pragma unroll
        for (int i = 0; i < 2; ++i)
#pragma unroll
            for (int j = 0; j < 4; ++j)
                acc[i][j] = __builtin_amdgcn_mfma_f32_16x16x32_bf16(
                    af[i], bfr[j], acc[i][j], 0, 0, 0);
        __syncthreads();
    }

    const int col = lane & 15, rq = (lane >> 4) * 4;
#pragma unroll
    for (int i = 0; i < 2; ++i)
#pragma unroll
        for (int j = 0; j < 4; ++j)
#pragma unroll
            for (int r = 0; r < 4; ++r)
                C[(m0 + i * 16 + rq + r) * (long)R_DIM + wave * 64 + j * 16 + col]
                    = acc[i][j][r];
}

// ===========================================================================
// MFMA NT GEMM, fp32 A converted during staging (mid-tier fallback K4).
// ===========================================================================
__global__ __launch_bounds__(256)
void gemm_mfma_a32(const float* __restrict__ A,
                   const unsigned short* __restrict__ B,
                   float* __restrict__ C, int M, int N, int Kc)
{
    __shared__ __align__(16) unsigned short As[128 * 32];
    __shared__ __align__(16) unsigned short Bs[128 * 32];

    const int tid  = threadIdx.x;
    const int wave = tid >> 6, lane = tid & 63;
    const int wm = wave >> 1, wn = wave & 1;
    const long m0 = (long)blockIdx.y * 128;
    const long n0 = (long)blockIdx.x * 128;

    f32x4 acc[4][4] = {};
    const int srow  = lane >> 2, skoff = (lane & 3) * 8;
    const int c0 = wave, c1 = wave + 4;
    const int kq = (lane >> 4) * 8, mr = lane & 15;
    const int arow = tid >> 1, ahalf = (tid & 1) * 16;

    for (int k0 = 0; k0 < Kc; k0 += 32) {
        gl2lds16(B + (n0 + c0 * 16 + srow) * (long)Kc + k0 + skoff, &Bs[c0 * 512]);
        gl2lds16(B + (n0 + c1 * 16 + srow) * (long)Kc + k0 + skoff, &Bs[c1 * 512]);
        {
            const float* g = A + (m0 + arow) * (long)Kc + k0 + ahalf;
            float4 v0 = *(const float4*)(g + 0);
            float4 v1 = *(const float4*)(g + 4);
            float4 v2 = *(const float4*)(g + 8);
            float4 v3 = *(const float4*)(g + 12);
            u16x8 u0, u1;
            u0[0] = f2bf(v0.x); u0[1] = f2bf(v0.y); u0[2] = f2bf(v0.z); u0[3] = f2bf(v0.w);
            u0[4] = f2bf(v1.x); u0[5] = f2bf(v1.y); u0[6] = f2bf(v1.z); u0[7] = f2bf(v1.w);
            u1[0] = f2bf(v2.x); u1[1] = f2bf(v2.y); u1[2] = f2bf(v2.z); u1[3] = f2bf(v2.w);
            u1[4] = f2bf(v3.x); u1[5] = f2bf(v3.y); u1[6] = f2bf(v3.z); u1[7] = f2bf(v3.w);
            *(u16x8*)&As[arow * 32 + ahalf + 0] = u0;
            *(u16x8*)&As[arow * 32 + ahalf + 8] = u1;
        }
        __syncthreads();
        bf16x8 af[4], bfr[4];
#pragma unroll
        for (int t = 0; t < 4; ++t) {
            af[t]  = *(const bf16x8*)&As[(wm * 64 + t * 16 + mr) * 32 + kq];
            bfr[t] = *(const bf16x8*)&Bs[(wn * 64 + t * 16 + mr) * 32 + kq];
        }
#pragma unroll
        for (int i = 0; i < 4; ++i)
#pragma unroll
            for (int j = 0; j < 4; ++j)
                acc[i][j] = __builtin_amdgcn_mfma_f32_16x16x32_bf16(
                    af[i], bfr[j], acc[i][j], 0, 0, 0);
        __syncthreads();
    }
    const int col = lane & 15, rquad = (lane >> 4) * 4;
#pragma unroll
    for (int i = 0; i < 4; ++i) {
        const long mrow = m0 + wm * 64 + i * 16 + rquad;
#pragma unroll
        for (int j = 0; j < 4; ++j) {
            float* p = C + mrow * (long)N + n0 + wn * 64 + j * 16 + col;
#pragma unroll
            for (int r = 0; r < 4; ++r) p[(long)r * N] = acc[i][j][r];
        }
    }
}

// ===========================================================================
// Prep kernels
// ===========================================================================
__global__ __launch_bounds__(256)
void prep_A(const float* __restrict__ P, unsigned short* __restrict__ Ap)
{
    const long i = (long)blockIdx.x * 256 + threadIdx.x;
    const long n = i >> 8; const int r = (int)(i & 255);
    const float x = P[i];
    const unsigned short hi = f2bf(x);
    const unsigned short lo = f2bf(x - bf2f(hi));
    unsigned short* row = Ap + n * KP;
    row[r] = hi; row[R_DIM + r] = hi; row[2 * R_DIM + r] = lo;
}

__global__ __launch_bounds__(256)
void prep_B(const float* __restrict__ L, unsigned short* __restrict__ Bp)
{
    const long i = (long)blockIdx.x * 256 + threadIdx.x;
    const long k = i >> 8; const int r = (int)(i & 255);
    const float x = L[i];
    const unsigned short hi = f2bf(x);
    const unsigned short lo = f2bf(x - bf2f(hi));
    unsigned short* row = Bp + k * KP;
    row[r] = hi; row[R_DIM + r] = lo; row[2 * R_DIM + r] = hi;
}

__global__ __launch_bounds__(256)
void prep_LT(const float* __restrict__ L, unsigned short* __restrict__ LT)
{
    const long i = (long)blockIdx.x * 256 + threadIdx.x;
    const long r = i >> 12; const long k = i & 4095;
    LT[r * K_DIM + k] = f2bf(L[k * R_DIM + r]);
}

// ===========================================================================
// fp32 VALU GEMM (K1 and low-tier fallback)
// ===========================================================================
template<bool BT>
__global__ __launch_bounds__(256)
void gemm128(const float* __restrict__ A, const float* __restrict__ B,
             float* __restrict__ C, int M, int N, int Kc)
{
    __shared__ __align__(16) float Asl[16][132];
    __shared__ __align__(16) float Bsl[16][132];
    const int tid = threadIdx.x;
    const int tx = tid & 15, ty = tid >> 4;
    const long m0 = (long)blockIdx.x * 128;
    const long n0 = (long)blockIdx.y * 128;
    float acc[8][8];
#pragma unroll
    for (int i = 0; i < 8; ++i)
#pragma unroll
        for (int j = 0; j < 8; ++j) acc[i][j] = 0.f;
    for (int k0 = 0; k0 < Kc; k0 += 16) {
#pragma unroll
        for (int q = 0; q < 2; ++q) {
            int fi = tid + 256 * q, row = fi >> 2, col = (fi & 3) * 4;
            float4 v = *(const float4*)(A + (m0 + row) * (long)Kc + k0 + col);
            Asl[col + 0][row] = v.x; Asl[col + 1][row] = v.y;
            Asl[col + 2][row] = v.z; Asl[col + 3][row] = v.w;
        }
        if (BT) {
#pragma unroll
            for (int q = 0; q < 2; ++q) {
                int fi = tid + 256 * q, row = fi >> 2, col = (fi & 3) * 4;
                float4 v = *(const float4*)(B + (n0 + row) * (long)Kc + k0 + col);
                Bsl[col + 0][row] = v.x; Bsl[col + 1][row] = v.y;
                Bsl[col + 2][row] = v.z; Bsl[col + 3][row] = v.w;
            }
        } else {
#pragma unroll
            for (int q = 0; q < 2; ++q) {
                int fi = tid + 256 * q, row = fi >> 5, col = (fi & 31) * 4;
                float4 v = *(const float4*)(B + (k0 + row) * (long)N + n0 + col);
                *(float4*)&Bsl[row][col] = v;
            }
        }
        __syncthreads();
#pragma unroll
        for (int kk = 0; kk < 16; ++kk) {
            float a[8], b[8];
            *(float4*)&a[0] = *(const float4*)&Asl[kk][ty * 8];
            *(float4*)&a[4] = *(const float4*)&Asl[kk][ty * 8 + 4];
            *(float4*)&b[0] = *(const float4*)&Bsl[kk][tx * 8];
            *(float4*)&b[4] = *(const float4*)&Bsl[kk][tx * 8 + 4];
#pragma unroll
            for (int i = 0; i < 8; ++i)
#pragma unroll
                for (int j = 0; j < 8; ++j)
                    acc[i][j] = fmaf(a[i], b[j], acc[i][j]);
        }
        __syncthreads();
    }
#pragma unroll
    for (int i = 0; i < 8; ++i) {
        float* p = C + (m0 + ty * 8 + i) * (long)N + n0 + tx * 8;
        *(float4*)p       = make_float4(acc[i][0], acc[i][1], acc[i][2], acc[i][3]);
        *(float4*)(p + 4) = make_float4(acc[i][4], acc[i][5], acc[i][6], acc[i][7]);
    }
}

// ---------------------------------------------------------------------------
// In-place row softmax (mid/low-tier fallback)
// ---------------------------------------------------------------------------
__global__ __launch_bounds__(256)
void softmax_rows(float* __restrict__ Mio)
{
    const long n  = blockIdx.x;
    float* row    = Mio + n * (long)K_DIM;
    const int tid = threadIdx.x;
    float4 v[4];
    float lmax = -3.4e38f;
#pragma unroll
    for (int q = 0; q < 4; ++q) {
        v[q] = ((const float4*)row)[tid + 256 * q];
        lmax = fmaxf(lmax, fmaxf(fmaxf(v[q].x, v[q].y), fmaxf(v[q].z, v[q].w)));
    }
    __shared__ float redmax[4], redsum[4];
#pragma unroll
    for (int off = 32; off > 0; off >>= 1)
        lmax = fmaxf(lmax, __shfl_xor(lmax, off));
    if ((tid & 63) == 0) redmax[tid >> 6] = lmax;
    __syncthreads();
    const float gmax = fmaxf(fmaxf(redmax[0], redmax[1]), fmaxf(redmax[2], redmax[3]));
    float lsum = 0.f;
#pragma unroll
    for (int q = 0; q < 4; ++q) {
        v[q].x = __expf(v[q].x - gmax); v[q].y = __expf(v[q].y - gmax);
        v[q].z = __expf(v[q].z - gmax); v[q].w = __expf(v[q].w - gmax);
        lsum += v[q].x + v[q].y + v[q].z + v[q].w;
    }
#pragma unroll
    for (int off = 32; off > 0; off >>= 1)
        lsum += __shfl_xor(lsum, off);
    if ((tid & 63) == 0) redsum[tid >> 6] = lsum;
    __syncthreads();
    const float inv = 1.f / (redsum[0] + redsum[1] + redsum[2] + redsum[3]);
#pragma unroll
    for (int q = 0; q < 4; ++q) {
        v[q].x *= inv; v[q].y *= inv; v[q].z *= inv; v[q].w *= inv;
        ((float4*)row)[tid + 256 * q] = v[q];
    }
}

// ===========================================================================
extern "C" void kernel_launch(void* const* d_in, const int* in_sizes, int n_in,
                              void* d_out, int out_size, void* d_ws, size_t ws_size,
                              hipStream_t stream)
{
    const float* H  = (const float*)d_in[0];
    const float* L  = (const float*)d_in[1];
    const float* Wi = (const float*)d_in[2];

    float* Cout = (float*)d_out;                           // N x R
    float* Aout = (float*)d_out + (size_t)N_ROWS * R_DIM;  // N x K

    const size_t szAp = (size_t)N_ROWS * KP * 2;     // 48 MiB
    const size_t szBp = (size_t)K_DIM * KP * 2;      //  6 MiB
    const size_t szLT = (size_t)R_DIM * K_DIM * 2;   //  2 MiB
    const size_t szPM = (size_t)N_ROWS * 32 * 4;     //  4 MiB
    const size_t szRM = (size_t)N_ROWS * 4;          //  128 KiB

    if (ws_size >= szAp + szBp + szLT + 2 * szPM + 2 * szRM) {
        char* w = (char*)d_ws;
        unsigned short* Ap = (unsigned short*)w;             w += szAp;
        unsigned short* Bp = (unsigned short*)w;             w += szBp;
        unsigned short* LT = (unsigned short*)w;             w += szLT;
        float* partM  = (float*)w;                           w += szPM;
        float* partL  = (float*)w;                           w += szPM;
        float* rowM   = (float*)w;                           w += szRM;
        float* rowInv = (float*)w;

        // K1: P = H@W_I (fp32 VALU) into C slot
        gemm128<false><<<dim3(N_ROWS / 128, R_DIM / 128), 256, 0, stream>>>(
            H, Wi, Cout, N_ROWS, R_DIM, R_DIM);
        prep_A<<<dim3((N_ROWS * R_DIM) / 256), 256, 0, stream>>>(Cout, Ap);
        prep_B<<<dim3((K_DIM * R_DIM) / 256), 256, 0, stream>>>(L, Bp);
        prep_LT<<<dim3((R_DIM * K_DIM) / 256), 256, 0, stream>>>(L, LT);
        // K2: logits + per-tile softmax partials
        gemm_mfma_nt<true><<<dim3(K_DIM / 128, N_ROWS / 128), 256, 0, stream>>>(
            Ap, Bp, Aout, N_ROWS, K_DIM, KP, partM, partL);
        // combine partials
        stats_combine<<<dim3(N_ROWS / 256), 256, 0, stream>>>(
            partM, partL, rowM, rowInv);
        // fused: A = softmax(M) written in place, C = A@L
        fused_aw<<<dim3(N_ROWS / 32), 256, 0, stream>>>(
            Aout, LT, rowM, rowInv, Cout);
    } else if (ws_size >= szAp + szBp + szLT) {
        unsigned short* Ap = (unsigned short*)d_ws;
        unsigned short* Bp = (unsigned short*)((char*)d_ws + szAp);
        unsigned short* LT = (unsigned short*)((char*)d_ws + szAp + szBp);
        gemm128<false><<<dim3(N_ROWS / 128, R_DIM / 128), 256, 0, stream>>>(
            H, Wi, Cout, N_ROWS, R_DIM, R_DIM);
        prep_A<<<dim3((N_ROWS * R_DIM) / 256), 256, 0, stream>>>(Cout, Ap);
        prep_B<<<dim3((K_DIM * R_DIM) / 256), 256, 0, stream>>>(L, Bp);
        prep_LT<<<dim3((R_DIM * K_DIM) / 256), 256, 0, stream>>>(L, LT);
        gemm_mfma_nt<false><<<dim3(K_DIM / 128, N_ROWS / 128), 256, 0, stream>>>(
            Ap, Bp, Aout, N_ROWS, K_DIM, KP, nullptr, nullptr);
        softmax_rows<<<dim3(N_ROWS), 256, 0, stream>>>(Aout);
        gemm_mfma_a32<<<dim3(R_DIM / 128, N_ROWS / 128), 256, 0, stream>>>(
            Aout, LT, Cout, N_ROWS, R_DIM, K_DIM);
    } else {
        gemm128<false><<<dim3(N_ROWS / 128, R_DIM / 128), 256, 0, stream>>>(
            H, Wi, Cout, N_ROWS, R_DIM, R_DIM);
        gemm128<true><<<dim3(N_ROWS / 128, K_DIM / 128), 256, 0, stream>>>(
            Cout, L, Aout, N_ROWS, K_DIM, R_DIM);
        softmax_rows<<<dim3(N_ROWS), 256, 0, stream>>>(Aout);
        gemm128<false><<<dim3(N_ROWS / 128, R_DIM / 128), 256, 0, stream>>>(
            Aout, L, Cout, N_ROWS, R_DIM, K_DIM);
    }
}

// Round 4
// 1344.607 us; speedup vs baseline: 1.0635x; 1.0635x over previous
//
#include <hip/hip_runtime.h>
#include <hip/hip_bf16.h>
#include <math.h>
#include <stdint.h>

// Problem constants
constexpr int N_ROWS = 32768;
constexpr int K_DIM  = 4096;
constexpr int R_DIM  = 256;
constexpr int KP     = 3 * R_DIM;   // 768: split-K' for [hi|hi|lo] x [hi|lo|hi]

typedef __bf16 bf16x8 __attribute__((ext_vector_type(8)));
typedef float  f32x4  __attribute__((ext_vector_type(4)));
typedef unsigned short u16x8 __attribute__((ext_vector_type(8)));
typedef unsigned short u16x4 __attribute__((ext_vector_type(4)));

// ---- bf16 helpers (round-to-nearest-even) ----
__device__ __forceinline__ unsigned short f2bf(float x) {
    unsigned u = __float_as_uint(x);
    u += 0x7fffu + ((u >> 16) & 1u);
    return (unsigned short)(u >> 16);
}
__device__ __forceinline__ float bf2f(unsigned short h) {
    return __uint_as_float((unsigned)h << 16);
}

// ---- async global->LDS, 16B/lane, LDS dest = wave-uniform base + lane*16
__device__ __forceinline__ void gl2lds16(const void* gptr, void* lptr) {
    __builtin_amdgcn_global_load_lds(
        (const __attribute__((address_space(1))) unsigned int*)gptr,
        (__attribute__((address_space(3))) unsigned int*)lptr,
        16, 0, 0);
}

// ===========================================================================
// K2: MFMA NT GEMM: C[m,n] = sum_k A[m,k]*B[n,k], bf16 in, fp32 out.
// 128x128 tile, BK=32, 4 waves (2x2 of 64x64), 16x16x32 MFMA.
// Grid: x = N-tile (fast-varying -> A-strip L2 reuse), y = M-tile.
// NO stats epilogue (round-3 lesson: it costs occupancy, VGPR 68->88).
// ===========================================================================
__global__ __launch_bounds__(256)
void gemm_mfma_nt(const unsigned short* __restrict__ A,
                  const unsigned short* __restrict__ B,
                  float* __restrict__ C, int M, int N, int Kc)
{
    __shared__ __align__(16) unsigned short As[128 * 32];
    __shared__ __align__(16) unsigned short Bs[128 * 32];

    const int tid  = threadIdx.x;
    const int wave = tid >> 6, lane = tid & 63;
    const int wm = wave >> 1, wn = wave & 1;
    const long m0 = (long)blockIdx.y * 128;
    const long n0 = (long)blockIdx.x * 128;

    f32x4 acc[4][4] = {};

    const int srow  = lane >> 2;
    const int skoff = (lane & 3) * 8;
    const int c0 = wave, c1 = wave + 4;
    const int kq = (lane >> 4) * 8;
    const int mr = lane & 15;

    for (int k0 = 0; k0 < Kc; k0 += 32) {
        gl2lds16(A + (m0 + c0 * 16 + srow) * (long)Kc + k0 + skoff, &As[c0 * 512]);
        gl2lds16(A + (m0 + c1 * 16 + srow) * (long)Kc + k0 + skoff, &As[c1 * 512]);
        gl2lds16(B + (n0 + c0 * 16 + srow) * (long)Kc + k0 + skoff, &Bs[c0 * 512]);
        gl2lds16(B + (n0 + c1 * 16 + srow) * (long)Kc + k0 + skoff, &Bs[c1 * 512]);
        __syncthreads();

        bf16x8 af[4], bfr[4];
#pragma unroll
        for (int t = 0; t < 4; ++t) {
            af[t]  = *(const bf16x8*)&As[(wm * 64 + t * 16 + mr) * 32 + kq];
            bfr[t] = *(const bf16x8*)&Bs[(wn * 64 + t * 16 + mr) * 32 + kq];
        }
#pragma unroll
        for (int i = 0; i < 4; ++i)
#pragma unroll
            for (int j = 0; j < 4; ++j)
                acc[i][j] = __builtin_amdgcn_mfma_f32_16x16x32_bf16(
                    af[i], bfr[j], acc[i][j], 0, 0, 0);
        __syncthreads();
    }

    // C/D layout: col = lane&15, row = (lane>>4)*4 + reg
    const int col = lane & 15, rquad = (lane >> 4) * 4;
#pragma unroll
    for (int i = 0; i < 4; ++i) {
        const long mrow = m0 + wm * 64 + i * 16 + rquad;
#pragma unroll
        for (int j = 0; j < 4; ++j) {
            float* p = C + mrow * (long)N + n0 + wn * 64 + j * 16 + col;
#pragma unroll
            for (int r = 0; r < 4; ++r) p[(long)r * N] = acc[i][j][r];
        }
    }
}

// ===========================================================================
// K1 fused: P = H @ W_I (fp32 VALU GEMM) with epilogue writing the split
// operand Ap = [P_hi | P_hi | P_lo] directly (no P materialization).
// M=N_ROWS, N=R_DIM(=256), K=R_DIM. 128x128 tile, 8x8/thread.
// ===========================================================================
__global__ __launch_bounds__(256)
void k1_ap(const float* __restrict__ A, const float* __restrict__ B,
           unsigned short* __restrict__ Ap)
{
    __shared__ __align__(16) float Asl[16][132];
    __shared__ __align__(16) float Bsl[16][132];
    const int tid = threadIdx.x;
    const int tx = tid & 15, ty = tid >> 4;
    const long m0 = (long)blockIdx.x * 128;
    const long n0 = (long)blockIdx.y * 128;
    const int Kc = R_DIM, N = R_DIM;

    float acc[8][8];
#pragma unroll
    for (int i = 0; i < 8; ++i)
#pragma unroll
        for (int j = 0; j < 8; ++j) acc[i][j] = 0.f;

    for (int k0 = 0; k0 < Kc; k0 += 16) {
#pragma unroll
        for (int q = 0; q < 2; ++q) {
            int fi = tid + 256 * q, row = fi >> 2, col = (fi & 3) * 4;
            float4 v = *(const float4*)(A + (m0 + row) * (long)Kc + k0 + col);
            Asl[col + 0][row] = v.x; Asl[col + 1][row] = v.y;
            Asl[col + 2][row] = v.z; Asl[col + 3][row] = v.w;
        }
#pragma unroll
        for (int q = 0; q < 2; ++q) {
            int fi = tid + 256 * q, row = fi >> 5, col = (fi & 31) * 4;
            float4 v = *(const float4*)(B + (k0 + row) * (long)N + n0 + col);
            *(float4*)&Bsl[row][col] = v;
        }
        __syncthreads();
#pragma unroll
        for (int kk = 0; kk < 16; ++kk) {
            float a[8], b[8];
            *(float4*)&a[0] = *(const float4*)&Asl[kk][ty * 8];
            *(float4*)&a[4] = *(const float4*)&Asl[kk][ty * 8 + 4];
            *(float4*)&b[0] = *(const float4*)&Bsl[kk][tx * 8];
            *(float4*)&b[4] = *(const float4*)&Bsl[kk][tx * 8 + 4];
#pragma unroll
            for (int i = 0; i < 8; ++i)
#pragma unroll
                for (int j = 0; j < 8; ++j)
                    acc[i][j] = fmaf(a[i], b[j], acc[i][j]);
        }
        __syncthreads();
    }
    // Epilogue: split write [hi|hi|lo]
#pragma unroll
    for (int i = 0; i < 8; ++i) {
        const long row = m0 + ty * 8 + i;
        u16x8 hi8, lo8;
#pragma unroll
        for (int j = 0; j < 8; ++j) {
            const unsigned short h = f2bf(acc[i][j]);
            hi8[j] = h;
            lo8[j] = f2bf(acc[i][j] - bf2f(h));
        }
        unsigned short* p = Ap + row * KP + n0 + tx * 8;
        *(u16x8*)(p)              = hi8;
        *(u16x8*)(p + R_DIM)      = hi8;
        *(u16x8*)(p + 2 * R_DIM)  = lo8;
    }
}

// ===========================================================================
// Tail fused: per 32-row strip —
//  phase 1: stream M once, online per-row (max, sum-exp) -> registers/LDS
//  phase 2: A = exp(M-m)*inv written in place; C = A@L via bf16 MFMA w/ LT.
// ===========================================================================
__global__ __launch_bounds__(256)
void fused_saw(float* __restrict__ Mio, const unsigned short* __restrict__ LT,
               float* __restrict__ C)
{
    __shared__ __align__(16) unsigned short As[32 * 32];
    __shared__ __align__(16) unsigned short Bs[256 * 32];
    __shared__ float sm[32][8];
    __shared__ float ss[32][8];

    const int tid = threadIdx.x, wave = tid >> 6, lane = tid & 63;
    const long m0 = (long)blockIdx.x * 32;

    const int arow = tid >> 3;           // 0..31 — row owned in both phases
    const int acol = (tid & 7) * 4;      // 0..28 — col offset within 32-chunk
    float* Mrow = Mio + (m0 + arow) * (long)K_DIM;

    // ---- phase 1: online (max, sum-exp) over this thread's 512 elements
    {
        float m = -3.4e38f, s = 0.f;
        const float* rp = Mrow + acol;
#pragma unroll 4
        for (int q = 0; q < 128; ++q) {
            float4 v = *(const float4*)(rp + 32 * q);
            float m4 = fmaxf(fmaxf(v.x, v.y), fmaxf(v.z, v.w));
            if (m4 > m) { s *= __expf(m - m4); m = m4; }
            s += __expf(v.x - m) + __expf(v.y - m)
               + __expf(v.z - m) + __expf(v.w - m);
        }
        sm[arow][tid & 7] = m;
        ss[arow][tid & 7] = s;
    }
    __syncthreads();
    float rm, ri;
    {
        float m = sm[arow][0];
#pragma unroll
        for (int t = 1; t < 8; ++t) m = fmaxf(m, sm[arow][t]);
        float S = 0.f;
#pragma unroll
        for (int t = 0; t < 8; ++t) S += ss[arow][t] * __expf(sm[arow][t] - m);
        rm = m; ri = 1.f / S;
    }
    __syncthreads();

    // ---- phase 2: normalize + write A + MFMA C = A@L
    const int srow = lane >> 2, skoff = (lane & 3) * 8;
    const int kq = (lane >> 4) * 8, mr = lane & 15;

    f32x4 acc[2][4] = {};

    for (int k0 = 0; k0 < K_DIM; k0 += 32) {
        // stage L^T chunk (256 n-rows x 32 k, bf16) via async DMA
#pragma unroll
        for (int c4 = 0; c4 < 4; ++c4) {
            const int c = wave * 4 + c4;
            gl2lds16(LT + (c * 16 + srow) * (long)K_DIM + k0 + skoff, &Bs[c * 512]);
        }
        // A chunk: read M, exp-normalize, write A back, bf16 to LDS
        float4 v = *(const float4*)(Mrow + k0 + acol);
        float4 a;
        a.x = __expf(v.x - rm) * ri;
        a.y = __expf(v.y - rm) * ri;
        a.z = __expf(v.z - rm) * ri;
        a.w = __expf(v.w - rm) * ri;
        *(float4*)(Mrow + k0 + acol) = a;
        u16x4 u;
        u[0] = f2bf(a.x); u[1] = f2bf(a.y); u[2] = f2bf(a.z); u[3] = f2bf(a.w);
        *(u16x4*)&As[arow * 32 + acol] = u;
        __syncthreads();

        bf16x8 af[2], bfr[4];
        af[0] = *(const bf16x8*)&As[(mr) * 32 + kq];
        af[1] = *(const bf16x8*)&As[(16 + mr) * 32 + kq];
#pragma unroll
        for (int j = 0; j < 4; ++j)
            bfr[j] = *(const bf16x8*)&Bs[(wave * 64 + j * 16 + mr) * 32 + kq];
#pragma unroll
        for (int i = 0; i < 2; ++i)
#pragma unroll
            for (int j = 0; j < 4; ++j)
                acc[i][j] = __builtin_amdgcn_mfma_f32_16x16x32_bf16(
                    af[i], bfr[j], acc[i][j], 0, 0, 0);
        __syncthreads();
    }

    const int col = lane & 15, rq = (lane >> 4) * 4;
#pragma unroll
    for (int i = 0; i < 2; ++i)
#pragma unroll
        for (int j = 0; j < 4; ++j)
#pragma unroll
            for (int r = 0; r < 4; ++r)
                C[(m0 + i * 16 + rq + r) * (long)R_DIM + wave * 64 + j * 16 + col]
                    = acc[i][j][r];
}

// ===========================================================================
// Prep kernels (L-derived operands)
// ===========================================================================
__global__ __launch_bounds__(256)
void prep_B(const float* __restrict__ L, unsigned short* __restrict__ Bp)
{
    const long i = (long)blockIdx.x * 256 + threadIdx.x;
    const long k = i >> 8; const int r = (int)(i & 255);
    const float x = L[i];
    const unsigned short hi = f2bf(x);
    const unsigned short lo = f2bf(x - bf2f(hi));
    unsigned short* row = Bp + k * KP;
    row[r] = hi; row[R_DIM + r] = lo; row[2 * R_DIM + r] = hi;
}

__global__ __launch_bounds__(256)
void prep_LT(const float* __restrict__ L, unsigned short* __restrict__ LT)
{
    const long i = (long)blockIdx.x * 256 + threadIdx.x;
    const long r = i >> 12; const long k = i & 4095;
    LT[r * K_DIM + k] = f2bf(L[k * R_DIM + r]);
}

// prep_A only used by mid-tier fallback (P materialized in Cout)
__global__ __launch_bounds__(256)
void prep_A(const float* __restrict__ P, unsigned short* __restrict__ Ap)
{
    const long i = (long)blockIdx.x * 256 + threadIdx.x;
    const long n = i >> 8; const int r = (int)(i & 255);
    const float x = P[i];
    const unsigned short hi = f2bf(x);
    const unsigned short lo = f2bf(x - bf2f(hi));
    unsigned short* row = Ap + n * KP;
    row[r] = hi; row[R_DIM + r] = hi; row[2 * R_DIM + r] = lo;
}

// ===========================================================================
// Fallback kernels (mid/low tiers) — unchanged from round 2
// ===========================================================================
__global__ __launch_bounds__(256)
void gemm_mfma_a32(const float* __restrict__ A,
                   const unsigned short* __restrict__ B,
                   float* __restrict__ C, int M, int N, int Kc)
{
    __shared__ __align__(16) unsigned short As[128 * 32];
    __shared__ __align__(16) unsigned short Bs[128 * 32];

    const int tid  = threadIdx.x;
    const int wave = tid >> 6, lane = tid & 63;
    const int wm = wave >> 1, wn = wave & 1;
    const long m0 = (long)blockIdx.y * 128;
    const long n0 = (long)blockIdx.x * 128;

    f32x4 acc[4][4] = {};
    const int srow  = lane >> 2, skoff = (lane & 3) * 8;
    const int c0 = wave, c1 = wave + 4;
    const int kq = (lane >> 4) * 8, mr = lane & 15;
    const int arow = tid >> 1, ahalf = (tid & 1) * 16;

    for (int k0 = 0; k0 < Kc; k0 += 32) {
        gl2lds16(B + (n0 + c0 * 16 + srow) * (long)Kc + k0 + skoff, &Bs[c0 * 512]);
        gl2lds16(B + (n0 + c1 * 16 + srow) * (long)Kc + k0 + skoff, &Bs[c1 * 512]);
        {
            const float* g = A + (m0 + arow) * (long)Kc + k0 + ahalf;
            float4 v0 = *(const float4*)(g + 0);
            float4 v1 = *(const float4*)(g + 4);
            float4 v2 = *(const float4*)(g + 8);
            float4 v3 = *(const float4*)(g + 12);
            u16x8 u0, u1;
            u0[0] = f2bf(v0.x); u0[1] = f2bf(v0.y); u0[2] = f2bf(v0.z); u0[3] = f2bf(v0.w);
            u0[4] = f2bf(v1.x); u0[5] = f2bf(v1.y); u0[6] = f2bf(v1.z); u0[7] = f2bf(v1.w);
            u1[0] = f2bf(v2.x); u1[1] = f2bf(v2.y); u1[2] = f2bf(v2.z); u1[3] = f2bf(v2.w);
            u1[4] = f2bf(v3.x); u1[5] = f2bf(v3.y); u1[6] = f2bf(v3.z); u1[7] = f2bf(v3.w);
            *(u16x8*)&As[arow * 32 + ahalf + 0] = u0;
            *(u16x8*)&As[arow * 32 + ahalf + 8] = u1;
        }
        __syncthreads();
        bf16x8 af[4], bfr[4];
#pragma unroll
        for (int t = 0; t < 4; ++t) {
            af[t]  = *(const bf16x8*)&As[(wm * 64 + t * 16 + mr) * 32 + kq];
            bfr[t] = *(const bf16x8*)&Bs[(wn * 64 + t * 16 + mr) * 32 + kq];
        }
#pragma unroll
        for (int i = 0; i < 4; ++i)
#pragma unroll
            for (int j = 0; j < 4; ++j)
                acc[i][j] = __builtin_amdgcn_mfma_f32_16x16x32_bf16(
                    af[i], bfr[j], acc[i][j], 0, 0, 0);
        __syncthreads();
    }
    const int col = lane & 15, rquad = (lane >> 4) * 4;
#pragma unroll
    for (int i = 0; i < 4; ++i) {
        const long mrow = m0 + wm * 64 + i * 16 + rquad;
#pragma unroll
        for (int j = 0; j < 4; ++j) {
            float* p = C + mrow * (long)N + n0 + wn * 64 + j * 16 + col;
#pragma unroll
            for (int r = 0; r < 4; ++r) p[(long)r * N] = acc[i][j][r];
        }
    }
}

template<bool BT>
__global__ __launch_bounds__(256)
void gemm128(const float* __restrict__ A, const float* __restrict__ B,
             float* __restrict__ C, int M, int N, int Kc)
{
    __shared__ __align__(16) float Asl[16][132];
    __shared__ __align__(16) float Bsl[16][132];
    const int tid = threadIdx.x;
    const int tx = tid & 15, ty = tid >> 4;
    const long m0 = (long)blockIdx.x * 128;
    const long n0 = (long)blockIdx.y * 128;
    float acc[8][8];
#pragma unroll
    for (int i = 0; i < 8; ++i)
#pragma unroll
        for (int j = 0; j < 8; ++j) acc[i][j] = 0.f;
    for (int k0 = 0; k0 < Kc; k0 += 16) {
#pragma unroll
        for (int q = 0; q < 2; ++q) {
            int fi = tid + 256 * q, row = fi >> 2, col = (fi & 3) * 4;
            float4 v = *(const float4*)(A + (m0 + row) * (long)Kc + k0 + col);
            Asl[col + 0][row] = v.x; Asl[col + 1][row] = v.y;
            Asl[col + 2][row] = v.z; Asl[col + 3][row] = v.w;
        }
        if (BT) {
#pragma unroll
            for (int q = 0; q < 2; ++q) {
                int fi = tid + 256 * q, row = fi >> 2, col = (fi & 3) * 4;
                float4 v = *(const float4*)(B + (n0 + row) * (long)Kc + k0 + col);
                Bsl[col + 0][row] = v.x; Bsl[col + 1][row] = v.y;
                Bsl[col + 2][row] = v.z; Bsl[col + 3][row] = v.w;
            }
        } else {
#pragma unroll
            for (int q = 0; q < 2; ++q) {
                int fi = tid + 256 * q, row = fi >> 5, col = (fi & 31) * 4;
                float4 v = *(const float4*)(B + (k0 + row) * (long)N + n0 + col);
                *(float4*)&Bsl[row][col] = v;
            }
        }
        __syncthreads();
#pragma unroll
        for (int kk = 0; kk < 16; ++kk) {
            float a[8], b[8];
            *(float4*)&a[0] = *(const float4*)&Asl[kk][ty * 8];
            *(float4*)&a[4] = *(const float4*)&Asl[kk][ty * 8 + 4];
            *(float4*)&b[0] = *(const float4*)&Bsl[kk][tx * 8];
            *(float4*)&b[4] = *(const float4*)&Bsl[kk][tx * 8 + 4];
#pragma unroll
            for (int i = 0; i < 8; ++i)
#pragma unroll
                for (int j = 0; j < 8; ++j)
                    acc[i][j] = fmaf(a[i], b[j], acc[i][j]);
        }
        __syncthreads();
    }
#pragma unroll
    for (int i = 0; i < 8; ++i) {
        float* p = C + (m0 + ty * 8 + i) * (long)N + n0 + tx * 8;
        *(float4*)p       = make_float4(acc[i][0], acc[i][1], acc[i][2], acc[i][3]);
        *(float4*)(p + 4) = make_float4(acc[i][4], acc[i][5], acc[i][6], acc[i][7]);
    }
}

__global__ __launch_bounds__(256)
void softmax_rows(float* __restrict__ Mio)
{
    const long n  = blockIdx.x;
    float* row    = Mio + n * (long)K_DIM;
    const int tid = threadIdx.x;
    float4 v[4];
    float lmax = -3.4e38f;
#pragma unroll
    for (int q = 0; q < 4; ++q) {
        v[q] = ((const float4*)row)[tid + 256 * q];
        lmax = fmaxf(lmax, fmaxf(fmaxf(v[q].x, v[q].y), fmaxf(v[q].z, v[q].w)));
    }
    __shared__ float redmax[4], redsum[4];
#pragma unroll
    for (int off = 32; off > 0; off >>= 1)
        lmax = fmaxf(lmax, __shfl_xor(lmax, off));
    if ((tid & 63) == 0) redmax[tid >> 6] = lmax;
    __syncthreads();
    const float gmax = fmaxf(fmaxf(redmax[0], redmax[1]), fmaxf(redmax[2], redmax[3]));
    float lsum = 0.f;
#pragma unroll
    for (int q = 0; q < 4; ++q) {
        v[q].x = __expf(v[q].x - gmax); v[q].y = __expf(v[q].y - gmax);
        v[q].z = __expf(v[q].z - gmax); v[q].w = __expf(v[q].w - gmax);
        lsum += v[q].x + v[q].y + v[q].z + v[q].w;
    }
#pragma unroll
    for (int off = 32; off > 0; off >>= 1)
        lsum += __shfl_xor(lsum, off);
    if ((tid & 63) == 0) redsum[tid >> 6] = lsum;
    __syncthreads();
    const float inv = 1.f / (redsum[0] + redsum[1] + redsum[2] + redsum[3]);
#pragma unroll
    for (int q = 0; q < 4; ++q) {
        v[q].x *= inv; v[q].y *= inv; v[q].z *= inv; v[q].w *= inv;
        ((float4*)row)[tid + 256 * q] = v[q];
    }
}

// ===========================================================================
extern "C" void kernel_launch(void* const* d_in, const int* in_sizes, int n_in,
                              void* d_out, int out_size, void* d_ws, size_t ws_size,
                              hipStream_t stream)
{
    const float* H  = (const float*)d_in[0];
    const float* L  = (const float*)d_in[1];
    const float* Wi = (const float*)d_in[2];

    float* Cout = (float*)d_out;                           // N x R
    float* Aout = (float*)d_out + (size_t)N_ROWS * R_DIM;  // N x K

    const size_t szAp = (size_t)N_ROWS * KP * 2;     // 48 MiB
    const size_t szBp = (size_t)K_DIM * KP * 2;      //  6 MiB
    const size_t szLT = (size_t)R_DIM * K_DIM * 2;   //  2 MiB

    if (ws_size >= szAp + szBp + szLT) {
        unsigned short* Ap = (unsigned short*)d_ws;
        unsigned short* Bp = (unsigned short*)((char*)d_ws + szAp);
        unsigned short* LT = (unsigned short*)((char*)d_ws + szAp + szBp);

        // K1 fused: P = H@W_I with split-epilogue -> Ap (no P materialization)
        k1_ap<<<dim3(N_ROWS / 128, R_DIM / 128), 256, 0, stream>>>(H, Wi, Ap);
        // L-derived operands
        prep_B<<<dim3((K_DIM * R_DIM) / 256), 256, 0, stream>>>(L, Bp);
        prep_LT<<<dim3((R_DIM * K_DIM) / 256), 256, 0, stream>>>(L, LT);
        // K2: logits M (N-tile fast-varying grid for A-strip L2 reuse)
        gemm_mfma_nt<<<dim3(K_DIM / 128, N_ROWS / 128), 256, 0, stream>>>(
            Ap, Bp, Aout, N_ROWS, K_DIM, KP);
        // Tail fused: stats + softmax-in-place + C = A@L
        fused_saw<<<dim3(N_ROWS / 32), 256, 0, stream>>>(Aout, LT, Cout);
    } else {
        // Fallback: round-1 fp32 path (no workspace requirements)
        gemm128<false><<<dim3(N_ROWS / 128, R_DIM / 128), 256, 0, stream>>>(
            H, Wi, Cout, N_ROWS, R_DIM, R_DIM);
        gemm128<true><<<dim3(N_ROWS / 128, K_DIM / 128), 256, 0, stream>>>(
            Cout, L, Aout, N_ROWS, K_DIM, R_DIM);
        softmax_rows<<<dim3(N_ROWS), 256, 0, stream>>>(Aout);
        gemm128<false><<<dim3(N_ROWS / 128, R_DIM / 128), 256, 0, stream>>>(
            Aout, L, Cout, N_ROWS, R_DIM, K_DIM);
    }
}